// Round 1
// baseline (6629.435 us; speedup 1.0000x reference)
//
#include <hip/hip_runtime.h>
#include <math.h>

// HierarchicalManifold: fully fused, one wave (64 lanes) per batch element.
// Lane l owns micro row l in registers; LDS holds cross-lane state.
// fp32 throughout (CDNA4 has no fp32 MFMA; workload is VALU-bound).
//
// LDS budget: 2*8192 (S ping/pong) + 8448 (scores, pad 66) + 2*4096 (traces)
//           + 3*2304 (M0/M1/QP, pad 36) + 256 (misc) = 40192 B -> 4 blocks/CU.

#define NMI   64
#define NMA   16
#define DD    32
#define NH    2
#define DHH   16
#define EH    64

#define F4(ptr) (*(const float4*)(ptr))

struct HMParams {
    const float* micro; const float* macro_; const float* tmi; const float* tma;
    const float* W_td; const float* b_td; const float* ln_g; const float* ln_b;
    const float* Wqkv; const float* bqkv; const float* Wo; const float* bo;
    const float* A_mi; const float* Ws_mi; const float* Wa_mi; const float* b_mi;
    const float* A_ma; const float* Ws_ma; const float* Wa_ma; const float* b_ma;
    const float* We1; const float* be1; const float* We2; const float* be2;
    const int* steps;
    float* out;
};

__device__ __forceinline__ float fast_tanh(float x) {
    // tanh(x) = 1 - 2/(exp(2x)+1); saturates correctly at +-1 for large |x|.
    float e = __expf(2.0f * x);
    return 1.0f - 2.0f / (e + 1.0f);
}

__global__ __launch_bounds__(64, 1) void hm_fused(HMParams p) {
    const int bid = blockIdx.x;
    const int l   = threadIdx.x;           // 0..63

    __shared__ float Sbuf[2][NMI][DD];     // micro states ping/pong; pong reused as vp
    __shared__ float SC[32][66];           // attention scores [h*16+q][k], pad 66
    __shared__ float Tmi[DD][DD];
    __shared__ float Tma[DD][DD];
    __shared__ float M0[NMA][36];          // macro states (canonical at step start)
    __shared__ float M1[NMA][36];          // post-LN macro
    __shared__ float QP[NMA][36];          // qp / attn-out / macro-agg scratch
    __shared__ float misc[64];             // [0..31] colmean, [32..63] 0.1*bias

    const int q4 = l >> 2;                 // macro row (4 lanes per row)
    const int c8 = (l & 3) * 8;            // macro col offset (8 cols per lane)
    const int td = l >> 1;                 // trace row (2 lanes per row)
    const int te = (l & 1) * 16;           // trace col offset

    float srow[DD];                        // this lane's micro row (always current)

    // ---------------- load ----------------
    {
        const float* g = p.micro + (size_t)bid * (NMI * DD) + (size_t)l * DD;
        #pragma unroll
        for (int c = 0; c < 8; ++c) {
            float4 v = F4(g + 4 * c);
            srow[4*c+0] = v.x; srow[4*c+1] = v.y; srow[4*c+2] = v.z; srow[4*c+3] = v.w;
            *(float4*)&Sbuf[0][l][4*c] = v;
        }
        const float* gt = p.tmi + (size_t)bid * (DD * DD) + l * 16;
        float* st = &Tmi[0][0] + l * 16;
        #pragma unroll
        for (int c = 0; c < 4; ++c) *(float4*)(st + 4*c) = F4(gt + 4*c);
        gt = p.tma + (size_t)bid * (DD * DD) + l * 16;
        st = &Tma[0][0] + l * 16;
        #pragma unroll
        for (int c = 0; c < 4; ++c) *(float4*)(st + 4*c) = F4(gt + 4*c);
        const float* gm = p.macro_ + (size_t)bid * (NMA * DD) + q4 * DD + c8;
        *(float4*)&M0[q4][c8]     = F4(gm);
        *(float4*)&M0[q4][c8 + 4] = F4(gm + 4);
    }
    const int nsteps = p.steps[0];
    __syncthreads();

    for (int s = 0; s < nsteps; ++s) {
        float (*Sold)[DD] = Sbuf[s & 1];
        float (*Snew)[DD] = Sbuf[(s & 1) ^ 1];

        // ---- phase 1: column means of macro ----
        if (l < DD) {
            float a = 0.f;
            #pragma unroll
            for (int n = 0; n < NMA; ++n) a += M0[n][l];
            misc[l] = a * (1.0f / NMA);
        }
        __syncthreads();
        // ---- phase 2: macro_bias[e] = colmean . W_td[e,:] + b_td[e], prescaled 0.1 ----
        if (l < DD) {
            float a = p.b_td[l];
            #pragma unroll
            for (int d4 = 0; d4 < 8; ++d4) {
                float4 w = F4(&p.W_td[l * DD + 4 * d4]);
                float4 m = F4(&misc[4 * d4]);
                a += m.x*w.x + m.y*w.y + m.z*w.z + m.w*w.w;
            }
            misc[DD + l] = 0.1f * a;
        }
        __syncthreads();
        // ---- phase 3: micro += 0.1*bias; mirror to Sold ----
        #pragma unroll
        for (int c = 0; c < 8; ++c) {
            float4 b = F4(&misc[DD + 4 * c]);
            srow[4*c+0] += b.x; srow[4*c+1] += b.y; srow[4*c+2] += b.z; srow[4*c+3] += b.w;
            *(float4*)&Sold[l][4*c] =
                make_float4(srow[4*c+0], srow[4*c+1], srow[4*c+2], srow[4*c+3]);
        }
        __syncthreads();

        // ---- phase 4: micro automata update ----
        {
            float acc[DD], agg[DD];
            #pragma unroll
            for (int c = 0; c < DD; ++c) { acc[c] = p.b_mi[c]; agg[c] = 0.f; }
            // heb: acc[e] += sum_d srow[d] * Tmi[d][e]   (uniform LDS broadcast)
            #pragma unroll
            for (int d = 0; d < DD; ++d) {
                float sd = srow[d];
                #pragma unroll
                for (int c = 0; c < 8; ++c) {
                    float4 t = F4(&Tmi[d][4*c]);
                    acc[4*c+0] += sd*t.x; acc[4*c+1] += sd*t.y;
                    acc[4*c+2] += sd*t.z; acc[4*c+3] += sd*t.w;
                }
            }
            // states@Ws: uniform weight -> scalar loads
            #pragma unroll
            for (int d = 0; d < DD; ++d) {
                float sd = srow[d];
                #pragma unroll
                for (int c = 0; c < 8; ++c) {
                    float4 w = F4(&p.Ws_mi[d * DD + 4*c]);
                    acc[4*c+0] += sd*w.x; acc[4*c+1] += sd*w.y;
                    acc[4*c+2] += sd*w.z; acc[4*c+3] += sd*w.w;
                }
            }
            // agg = A_mi[l,:] @ Sold  (LDS rows broadcast to all lanes)
            for (int n4 = 0; n4 < NMI / 4; ++n4) {
                float4 a4 = F4(&p.A_mi[l * NMI + 4 * n4]);
                const float* r0 = Sold[4*n4+0];
                const float* r1 = Sold[4*n4+1];
                const float* r2 = Sold[4*n4+2];
                const float* r3 = Sold[4*n4+3];
                #pragma unroll
                for (int c = 0; c < 8; ++c) {
                    float4 v0 = F4(r0 + 4*c), v1 = F4(r1 + 4*c);
                    float4 v2 = F4(r2 + 4*c), v3 = F4(r3 + 4*c);
                    agg[4*c+0] += a4.x*v0.x + a4.y*v1.x + a4.z*v2.x + a4.w*v3.x;
                    agg[4*c+1] += a4.x*v0.y + a4.y*v1.y + a4.z*v2.y + a4.w*v3.y;
                    agg[4*c+2] += a4.x*v0.z + a4.y*v1.z + a4.z*v2.z + a4.w*v3.z;
                    agg[4*c+3] += a4.x*v0.w + a4.y*v1.w + a4.z*v2.w + a4.w*v3.w;
                }
            }
            // acc[e] += sum_d agg[d] * Wa_mi[d][e]
            #pragma unroll
            for (int d = 0; d < DD; ++d) {
                float ad = agg[d];
                #pragma unroll
                for (int c = 0; c < 8; ++c) {
                    float4 w = F4(&p.Wa_mi[d * DD + 4*c]);
                    acc[4*c+0] += ad*w.x; acc[4*c+1] += ad*w.y;
                    acc[4*c+2] += ad*w.z; acc[4*c+3] += ad*w.w;
                }
            }
            // new = l2norm(states + 0.1*tanh(acc))
            float ss = 0.f;
            #pragma unroll
            for (int c = 0; c < DD; ++c) {
                float v = srow[c] + 0.1f * fast_tanh(acc[c]);
                acc[c] = v; ss += v * v;
            }
            float inv = 1.0f / (sqrtf(ss) + 1e-6f);
            #pragma unroll
            for (int c = 0; c < 8; ++c) {
                float4 v = make_float4(acc[4*c+0]*inv, acc[4*c+1]*inv,
                                       acc[4*c+2]*inv, acc[4*c+3]*inv);
                srow[4*c+0] = v.x; srow[4*c+1] = v.y; srow[4*c+2] = v.z; srow[4*c+3] = v.w;
                *(float4*)&Snew[l][4*c] = v;
            }
        }
        __syncthreads();

        // ---- phase 5: micro trace update + qp projection ----
        {
            float tacc[16];
            #pragma unroll
            for (int j = 0; j < 16; ++j) tacc[j] = 0.f;
            for (int n = 0; n < NMI; ++n) {
                float pd = Sold[n][td];
                #pragma unroll
                for (int c = 0; c < 4; ++c) {
                    float4 v = F4(&Snew[n][te + 4*c]);
                    tacc[4*c+0] += pd*v.x; tacc[4*c+1] += pd*v.y;
                    tacc[4*c+2] += pd*v.z; tacc[4*c+3] += pd*v.w;
                }
            }
            #pragma unroll
            for (int c = 0; c < 4; ++c) {
                float4 t = F4(&Tmi[td][te + 4*c]);
                t.x = 0.95f*t.x + (0.05f/NMI)*tacc[4*c+0];
                t.y = 0.95f*t.y + (0.05f/NMI)*tacc[4*c+1];
                t.z = 0.95f*t.z + (0.05f/NMI)*tacc[4*c+2];
                t.w = 0.95f*t.w + (0.05f/NMI)*tacc[4*c+3];
                *(float4*)&Tmi[td][te + 4*c] = t;
            }
        }
        {
            // qp[q4][c8+j] = bq[c8+j] + sum_d M0[q4][d] * Wqkv[(c8+j)*D + d]
            float mrow[DD];
            #pragma unroll
            for (int c = 0; c < 8; ++c) {
                float4 v = F4(&M0[q4][4*c]);
                mrow[4*c+0]=v.x; mrow[4*c+1]=v.y; mrow[4*c+2]=v.z; mrow[4*c+3]=v.w;
            }
            float qa[8];
            #pragma unroll
            for (int j = 0; j < 8; ++j) {
                float a = p.bqkv[c8 + j];
                #pragma unroll
                for (int d4 = 0; d4 < 8; ++d4) {
                    float4 w = F4(&p.Wqkv[(c8 + j) * DD + 4 * d4]);
                    a += mrow[4*d4+0]*w.x + mrow[4*d4+1]*w.y
                       + mrow[4*d4+2]*w.z + mrow[4*d4+3]*w.w;
                }
                qa[j] = a;
            }
            *(float4*)&QP[q4][c8]     = make_float4(qa[0], qa[1], qa[2], qa[3]);
            *(float4*)&QP[q4][c8 + 4] = make_float4(qa[4], qa[5], qa[6], qa[7]);
        }
        __syncthreads();

        // ---- phase 6: kp (regs), vp -> Sold, scores -> SC ----
        {
            float kp[DD];
            #pragma unroll
            for (int e = 0; e < DD; ++e) {
                float a = p.bqkv[DD + e];
                #pragma unroll
                for (int d4 = 0; d4 < 8; ++d4) {
                    float4 w = F4(&p.Wqkv[(DD + e) * DD + 4 * d4]);
                    a += srow[4*d4+0]*w.x + srow[4*d4+1]*w.y
                       + srow[4*d4+2]*w.z + srow[4*d4+3]*w.w;
                }
                kp[e] = a;
            }
            #pragma unroll
            for (int e4 = 0; e4 < 8; ++e4) {
                float vv[4];
                #pragma unroll
                for (int kk = 0; kk < 4; ++kk) {
                    const int e = 4 * e4 + kk;
                    float a = p.bqkv[2 * DD + e];
                    #pragma unroll
                    for (int d4 = 0; d4 < 8; ++d4) {
                        float4 w = F4(&p.Wqkv[(2 * DD + e) * DD + 4 * d4]);
                        a += srow[4*d4+0]*w.x + srow[4*d4+1]*w.y
                           + srow[4*d4+2]*w.z + srow[4*d4+3]*w.w;
                    }
                    vv[kk] = a;
                }
                *(float4*)&Sold[l][4*e4] = make_float4(vv[0], vv[1], vv[2], vv[3]);
            }
            // scores: SC[h*16+q][l] = 0.25 * qp[q][h*16+:] . kp[h*16+:]
            #pragma unroll
            for (int h = 0; h < NH; ++h) {
                for (int qq = 0; qq < NMA; ++qq) {
                    float a = 0.f;
                    #pragma unroll
                    for (int j4 = 0; j4 < 4; ++j4) {
                        float4 qv = F4(&QP[qq][h * DHH + 4 * j4]);
                        a += qv.x * kp[h*DHH + 4*j4 + 0] + qv.y * kp[h*DHH + 4*j4 + 1]
                           + qv.z * kp[h*DHH + 4*j4 + 2] + qv.w * kp[h*DHH + 4*j4 + 3];
                    }
                    SC[h * NMA + qq][l] = 0.25f * a;
                }
            }
        }
        __syncthreads();

        // ---- phase 7: softmax + PV (lanes 0..31, one (h,q) each) ----
        if (l < 32) {
            const int h = l >> 4, qq = l & 15;
            float mx = -1e30f;
            for (int k = 0; k < NMI; ++k) mx = fmaxf(mx, SC[l][k]);
            float oacc[DHH];
            #pragma unroll
            for (int j = 0; j < DHH; ++j) oacc[j] = 0.f;
            float den = 0.f;
            for (int k = 0; k < NMI; ++k) {
                float pv = __expf(SC[l][k] - mx);
                den += pv;
                #pragma unroll
                for (int j4 = 0; j4 < 4; ++j4) {
                    float4 v = F4(&Sold[k][h * DHH + 4 * j4]);   // vp
                    oacc[4*j4+0] += pv*v.x; oacc[4*j4+1] += pv*v.y;
                    oacc[4*j4+2] += pv*v.z; oacc[4*j4+3] += pv*v.w;
                }
            }
            float id = 1.0f / den;
            #pragma unroll
            for (int j4 = 0; j4 < 4; ++j4)
                *(float4*)&QP[qq][h * DHH + 4 * j4] =
                    make_float4(oacc[4*j4+0]*id, oacc[4*j4+1]*id,
                                oacc[4*j4+2]*id, oacc[4*j4+3]*id);
        }
        __syncthreads();

        // ---- phase 8: @Wo + residual + LayerNorm -> M1 ----
        {
            float orow[DD];
            #pragma unroll
            for (int c = 0; c < 8; ++c) {
                float4 v = F4(&QP[q4][4*c]);
                orow[4*c+0]=v.x; orow[4*c+1]=v.y; orow[4*c+2]=v.z; orow[4*c+3]=v.w;
            }
            float x[8];
            #pragma unroll
            for (int j = 0; j < 8; ++j) {
                float a = p.bo[c8 + j];
                #pragma unroll
                for (int e4 = 0; e4 < 8; ++e4) {
                    float4 w = F4(&p.Wo[(c8 + j) * DD + 4 * e4]);
                    a += orow[4*e4+0]*w.x + orow[4*e4+1]*w.y
                       + orow[4*e4+2]*w.z + orow[4*e4+3]*w.w;
                }
                x[j] = M0[q4][c8 + j] + a;
            }
            float s1 = x[0]+x[1]+x[2]+x[3]+x[4]+x[5]+x[6]+x[7];
            s1 += __shfl_xor(s1, 1); s1 += __shfl_xor(s1, 2);
            float mu = s1 * (1.0f / DD);
            float s2 = 0.f;
            #pragma unroll
            for (int j = 0; j < 8; ++j) { float dl = x[j] - mu; s2 += dl * dl; }
            s2 += __shfl_xor(s2, 1); s2 += __shfl_xor(s2, 2);
            float rs = rsqrtf(s2 * (1.0f / DD) + 1e-5f);
            float y[8];
            #pragma unroll
            for (int j = 0; j < 8; ++j)
                y[j] = (x[j] - mu) * rs * p.ln_g[c8 + j] + p.ln_b[c8 + j];
            *(float4*)&M1[q4][c8]     = make_float4(y[0], y[1], y[2], y[3]);
            *(float4*)&M1[q4][c8 + 4] = make_float4(y[4], y[5], y[6], y[7]);
        }
        __syncthreads();

        // ---- phase 9: macro agg = A_ma @ M1 -> QP ----
        {
            float ag[8];
            #pragma unroll
            for (int j = 0; j < 8; ++j) ag[j] = 0.f;
            #pragma unroll
            for (int n4 = 0; n4 < 4; ++n4) {
                float4 a4 = F4(&p.A_ma[q4 * NMA + 4 * n4]);
                #pragma unroll
                for (int nn = 0; nn < 4; ++nn) {
                    float a = (nn == 0) ? a4.x : (nn == 1) ? a4.y : (nn == 2) ? a4.z : a4.w;
                    float4 m0 = F4(&M1[4*n4+nn][c8]);
                    float4 m1v = F4(&M1[4*n4+nn][c8 + 4]);
                    ag[0] += a*m0.x;  ag[1] += a*m0.y;  ag[2] += a*m0.z;  ag[3] += a*m0.w;
                    ag[4] += a*m1v.x; ag[5] += a*m1v.y; ag[6] += a*m1v.z; ag[7] += a*m1v.w;
                }
            }
            *(float4*)&QP[q4][c8]     = make_float4(ag[0], ag[1], ag[2], ag[3]);
            *(float4*)&QP[q4][c8 + 4] = make_float4(ag[4], ag[5], ag[6], ag[7]);
        }
        __syncthreads();

        // ---- phase 10: macro automata update -> M0 ----
        {
            float mrow[DD], arow[DD];
            #pragma unroll
            for (int c = 0; c < 8; ++c) {
                float4 v = F4(&M1[q4][4*c]);
                mrow[4*c+0]=v.x; mrow[4*c+1]=v.y; mrow[4*c+2]=v.z; mrow[4*c+3]=v.w;
                float4 w = F4(&QP[q4][4*c]);
                arow[4*c+0]=w.x; arow[4*c+1]=w.y; arow[4*c+2]=w.z; arow[4*c+3]=w.w;
            }
            float u[8];
            #pragma unroll
            for (int j = 0; j < 8; ++j) u[j] = p.b_ma[c8 + j];
            #pragma unroll
            for (int d = 0; d < DD; ++d) {
                float md = mrow[d], ad = arow[d];
                float4 t0 = F4(&Tma[d][c8]);
                float4 t1 = F4(&Tma[d][c8 + 4]);
                float4 w0 = F4(&p.Ws_ma[d * DD + c8]);
                float4 w1 = F4(&p.Ws_ma[d * DD + c8 + 4]);
                float4 a0 = F4(&p.Wa_ma[d * DD + c8]);
                float4 a1 = F4(&p.Wa_ma[d * DD + c8 + 4]);
                u[0] += md*(t0.x + w0.x) + ad*a0.x;
                u[1] += md*(t0.y + w0.y) + ad*a0.y;
                u[2] += md*(t0.z + w0.z) + ad*a0.z;
                u[3] += md*(t0.w + w0.w) + ad*a0.w;
                u[4] += md*(t1.x + w1.x) + ad*a1.x;
                u[5] += md*(t1.y + w1.y) + ad*a1.y;
                u[6] += md*(t1.z + w1.z) + ad*a1.z;
                u[7] += md*(t1.w + w1.w) + ad*a1.w;
            }
            float4 mm0 = F4(&M1[q4][c8]);
            float4 mm1 = F4(&M1[q4][c8 + 4]);
            float base[8] = {mm0.x, mm0.y, mm0.z, mm0.w, mm1.x, mm1.y, mm1.z, mm1.w};
            float nv[8]; float ssp = 0.f;
            #pragma unroll
            for (int j = 0; j < 8; ++j) {
                float v = base[j] + 0.1f * fast_tanh(u[j]);
                nv[j] = v; ssp += v * v;
            }
            ssp += __shfl_xor(ssp, 1); ssp += __shfl_xor(ssp, 2);
            float invn = 1.0f / (sqrtf(ssp) + 1e-6f);
            #pragma unroll
            for (int j = 0; j < 8; ++j) nv[j] *= invn;
            *(float4*)&M0[q4][c8]     = make_float4(nv[0], nv[1], nv[2], nv[3]);
            *(float4*)&M0[q4][c8 + 4] = make_float4(nv[4], nv[5], nv[6], nv[7]);
        }
        __syncthreads();

        // ---- phase 11: macro trace update ----
        {
            float tacc[16];
            #pragma unroll
            for (int j = 0; j < 16; ++j) tacc[j] = 0.f;
            #pragma unroll
            for (int n = 0; n < NMA; ++n) {
                float pd = M1[n][td];
                #pragma unroll
                for (int c = 0; c < 4; ++c) {
                    float4 v = F4(&M0[n][te + 4*c]);
                    tacc[4*c+0] += pd*v.x; tacc[4*c+1] += pd*v.y;
                    tacc[4*c+2] += pd*v.z; tacc[4*c+3] += pd*v.w;
                }
            }
            #pragma unroll
            for (int c = 0; c < 4; ++c) {
                float4 t = F4(&Tma[td][te + 4*c]);
                t.x = 0.95f*t.x + (0.05f/NMA)*tacc[4*c+0];
                t.y = 0.95f*t.y + (0.05f/NMA)*tacc[4*c+1];
                t.z = 0.95f*t.z + (0.05f/NMA)*tacc[4*c+2];
                t.w = 0.95f*t.w + (0.05f/NMA)*tacc[4*c+3];
                *(float4*)&Tma[td][te + 4*c] = t;
            }
        }
        __syncthreads();
    }

    // ---- energy (reference overwrites each step -> only final value matters) ----
    float energy = 0.f;
    if (nsteps > 0) {
        float hacc[EH];
        #pragma unroll
        for (int e = 0; e < EH; ++e) hacc[e] = p.be1[e];
        #pragma unroll
        for (int d = 0; d < DD; ++d) {
            float sd = srow[d];
            #pragma unroll
            for (int e4 = 0; e4 < EH / 4; ++e4) {
                float4 w = F4(&p.We1[d * EH + 4 * e4]);
                hacc[4*e4+0] += sd*w.x; hacc[4*e4+1] += sd*w.y;
                hacc[4*e4+2] += sd*w.z; hacc[4*e4+3] += sd*w.w;
            }
        }
        float val = p.be2[0];
        #pragma unroll
        for (int e = 0; e < EH; ++e) val += fast_tanh(hacc[e]) * p.We2[e];
        val += __shfl_xor(val, 1);  val += __shfl_xor(val, 2);
        val += __shfl_xor(val, 4);  val += __shfl_xor(val, 8);
        val += __shfl_xor(val, 16); val += __shfl_xor(val, 32);
        energy = val * (1.0f / NMI);
    }

    // ---- outputs: [micro | macro | micro_trace | macro_trace | energy] ----
    const size_t NB = gridDim.x;
    const size_t o1 = NB * (NMI * DD);
    const size_t o2 = o1 + NB * (NMA * DD);
    const size_t o3 = o2 + NB * (DD * DD);
    const size_t o4 = o3 + NB * (DD * DD);
    {
        float* g = p.out + (size_t)bid * (NMI * DD) + (size_t)l * DD;
        #pragma unroll
        for (int c = 0; c < 8; ++c)
            *(float4*)(g + 4*c) = make_float4(srow[4*c+0], srow[4*c+1],
                                              srow[4*c+2], srow[4*c+3]);
    }
    {
        float* g = p.out + o1 + (size_t)bid * (NMA * DD) + q4 * DD + c8;
        *(float4*)(g)     = F4(&M0[q4][c8]);
        *(float4*)(g + 4) = F4(&M0[q4][c8 + 4]);
    }
    {
        float* g = p.out + o2 + (size_t)bid * (DD * DD) + l * 16;
        const float* t = &Tmi[0][0] + l * 16;
        #pragma unroll
        for (int c = 0; c < 4; ++c) *(float4*)(g + 4*c) = F4(t + 4*c);
        g = p.out + o3 + (size_t)bid * (DD * DD) + l * 16;
        t = &Tma[0][0] + l * 16;
        #pragma unroll
        for (int c = 0; c < 4; ++c) *(float4*)(g + 4*c) = F4(t + 4*c);
    }
    if (l == 0) p.out[o4 + bid] = energy;
}

extern "C" void kernel_launch(void* const* d_in, const int* in_sizes, int n_in,
                              void* d_out, int out_size, void* d_ws, size_t ws_size,
                              hipStream_t stream) {
    (void)n_in; (void)out_size; (void)d_ws; (void)ws_size;
    HMParams p;
    p.micro  = (const float*)d_in[0];
    p.macro_ = (const float*)d_in[1];
    p.tmi    = (const float*)d_in[2];
    p.tma    = (const float*)d_in[3];
    p.W_td   = (const float*)d_in[4];
    p.b_td   = (const float*)d_in[5];
    p.ln_g   = (const float*)d_in[6];
    p.ln_b   = (const float*)d_in[7];
    p.Wqkv   = (const float*)d_in[8];
    p.bqkv   = (const float*)d_in[9];
    p.Wo     = (const float*)d_in[10];
    p.bo     = (const float*)d_in[11];
    p.A_mi   = (const float*)d_in[12];
    p.Ws_mi  = (const float*)d_in[13];
    p.Wa_mi  = (const float*)d_in[14];
    p.b_mi   = (const float*)d_in[15];
    p.A_ma   = (const float*)d_in[16];
    p.Ws_ma  = (const float*)d_in[17];
    p.Wa_ma  = (const float*)d_in[18];
    p.b_ma   = (const float*)d_in[19];
    p.We1    = (const float*)d_in[20];
    p.be1    = (const float*)d_in[21];
    p.We2    = (const float*)d_in[22];
    p.be2    = (const float*)d_in[23];
    p.steps  = (const int*)d_in[24];
    p.out    = (float*)d_out;
    const int B = in_sizes[0] / (NMI * DD);
    hipLaunchKernelGGL(hm_fused, dim3(B), dim3(64), 0, stream, p);
}